// Round 10
// baseline (145.694 us; speedup 1.0000x reference)
//
#include <hip/hip_runtime.h>

// CapsuleNetwork routing, fused, one block per batch. B=2048, S=200, D=64, K=4.
//
// hat[b,k,s,:] = emb[b,s,:] @ W_k + b_k is never materialized:
//   logits[k,s] = emb[s]·u[k] + off[k],  u[k] = W_k @ G[k], off[k] = b_k·G[k]
//   v[k]        = e[k] @ W_k + ts[k]·b_k, e[k] = sum_s sw[k,s] emb[s]
// G = running sum of interests (cw telescopes).
//
// Round-10: LDS-pipe was the bottleneck (r9 model: ~55us LDS-inst time vs
// ~29us VALU; both pipes ~32% busy, serialized). Fuse B into D:
//  - ONE emb read per row per iteration (b128, lane j = chunk j), shared by
//    logit FMAs and e-accumulation.
//  - u[k] chunks in 16 VGPRs (4 b128 loads/lane/iter, not 4 per chunk-step).
//  - logits: 4-level shfl_xor butterfly within the 16-lane group; softmax
//    redundant in-lane; sw consumed from regs (no ssw LDS roundtrip).
//  - barriers 13 -> 10.
//  - launch_bounds(512,2): r8 proved (512,4) hard-caps VGPR at 64 (spill);
//    LDS 61.9KB keeps occupancy at 2 blocks/CU regardless, so VGPR~95 is free.

#define NB 2048
#define NS 200
#define ND 64
#define NK 4
#define NT 512

__device__ __forceinline__ float wred64(float v) {
#pragma unroll
  for (int o = 1; o < 64; o <<= 1) v += __shfl_xor(v, o, 64);
  return v;
}

__device__ __forceinline__ int rot(int s) { return (s + (s >> 3)) & 15; }

__device__ __forceinline__ void gload16(const float* g_, float* l_) {
  __builtin_amdgcn_global_load_lds(
      (const __attribute__((address_space(1))) unsigned int*)g_,
      (__attribute__((address_space(3))) unsigned int*)l_, 16, 0, 0);
}

#define RED_GRP(v) v += __shfl_xor(v, 16, 64); v += __shfl_xor(v, 32, 64);
#define RED_16(v)                                        \
  v += __shfl_xor(v, 1, 64); v += __shfl_xor(v, 2, 64);  \
  v += __shfl_xor(v, 4, 64); v += __shfl_xor(v, 8, 64);

__global__ __launch_bounds__(NT, 2) void caps_kernel(
    const float* __restrict__ his, const float* __restrict__ itemeb,
    const int* __restrict__ mask, const float* __restrict__ W,
    const float* __restrict__ bias, float* __restrict__ out) {
  __shared__ float semb[NS * ND];  // 51200B: row s, chunk c at slot (c+rot(s))&15
  __shared__ float pe[8][NK][ND];  // 8192B: per-wave BD partials
  __shared__ float sG[NK][ND];     // 1024B: running interest sum
  __shared__ float su[NK][ND];     // 1024B: u[k]; E1 se-bounce
  __shared__ float spv[NK][ND];    // 1024B: E h1 partials; interest stash
  __shared__ float smsk[NS];       // 800B
  __shared__ float pts[8][NK];     // 128B
  __shared__ __align__(16) float soff[NK];
  __shared__ float satt[NK];
  __shared__ int sidx;
  // total ~62 KB -> 2 blocks/CU (LDS-capped)

  const int t = threadIdx.x;
  const int w = t >> 6, l = t & 63;
  const int g = l >> 4, j = l & 15;  // 16-lane group / chunk
  const int gid = (w << 2) | g;      // 0..31
  const int ke = w & 3, h_ = w >> 2; // E roles
  const int b = blockIdx.x;
  const float* eb = his + (size_t)b * NS * ND;

  // ---- W slice in regs: wave (ke,h) owns W[32h..32h+32)[64ke+l] ----
  float wreg[32];
#pragma unroll
  for (int c = 0; c < 32; ++c)
    wreg[c] = W[(size_t)(32 * h_ + c) * (NK * ND) + ke * ND + l];
  float breg = bias[ke * ND + l];
  float iq = itemeb[(size_t)b * ND + l];

  // ---- stage all 200 rows (linear LDS dest, rotated global source) ----
  for (int i = w; i < 50; i += 8) {
    int s = 4 * i + g;
    int q = (j - rot(s)) & 15;  // global chunk that lands at slot j
    gload16(eb + (s << 6) + (q << 2), &semb[i * 256]);
  }
  if (t < NS) smsk[t] = (mask[(size_t)b * NS + t] != 0) ? 1.0f : 0.0f;
  __syncthreads();

  const int ntr = (w < 2) ? 7 : 6;  // wave-uniform trips (gid<8 covers s=199)

  for (int it = 0; it < 3; ++it) {
    // ---- fused BD: logits + softmax + e-accumulate in one sweep ----
    float4 a0 = {0, 0, 0, 0}, a1 = {0, 0, 0, 0}, a2 = {0, 0, 0, 0},
           a3 = {0, 0, 0, 0};
    float t0 = 0, t1 = 0, t2 = 0, t3 = 0;

    if (it == 0) {
      // sw = 0.25*mask for every k: accumulate k=0 only, replicate after
      for (int tt = 0; tt < ntr; ++tt) {
        int s = gid + 32 * tt;
        float4 eq = *(const float4*)&semb[(s << 6) + 4 * ((j + rot(s)) & 15)];
        float sw = 0.25f * smsk[s];
        a0.x += sw * eq.x; a0.y += sw * eq.y;
        a0.z += sw * eq.z; a0.w += sw * eq.w;
        t0 += sw;
      }
      RED_GRP(a0.x) RED_GRP(a0.y) RED_GRP(a0.z) RED_GRP(a0.w) RED_GRP(t0)
      a1 = a0; a2 = a0; a3 = a0; t1 = t0; t2 = t0; t3 = t0;
    } else {
      float4 u0 = *(const float4*)&su[0][4 * j];  // u chunks -> 16 VGPR
      float4 u1 = *(const float4*)&su[1][4 * j];
      float4 u2 = *(const float4*)&su[2][4 * j];
      float4 u3 = *(const float4*)&su[3][4 * j];
      float4 sof = *(const float4*)&soff[0];      // wave-broadcast
      for (int tt = 0; tt < ntr; ++tt) {
        int s = gid + 32 * tt;
        float4 eq = *(const float4*)&semb[(s << 6) + 4 * ((j + rot(s)) & 15)];
        float mk = smsk[s];
        // per-chunk logit partials, butterfly-reduced within the 16-group
        float lg0 = eq.x * u0.x + eq.y * u0.y + eq.z * u0.z + eq.w * u0.w;
        float lg1 = eq.x * u1.x + eq.y * u1.y + eq.z * u1.z + eq.w * u1.w;
        float lg2 = eq.x * u2.x + eq.y * u2.y + eq.z * u2.z + eq.w * u2.w;
        float lg3 = eq.x * u3.x + eq.y * u3.y + eq.z * u3.z + eq.w * u3.w;
        RED_16(lg0) RED_16(lg1) RED_16(lg2) RED_16(lg3)
        lg0 += sof.x; lg1 += sof.y; lg2 += sof.z; lg3 += sof.w;
        // in-lane softmax over k (redundant across the 16 lanes; no LDS)
        float mx = fmaxf(fmaxf(lg0, lg1), fmaxf(lg2, lg3));
        float e0 = __expf(lg0 - mx), e1 = __expf(lg1 - mx);
        float e2 = __expf(lg2 - mx), e3 = __expf(lg3 - mx);
        float r = mk / (e0 + e1 + e2 + e3);
        float sw0 = e0 * r, sw1 = e1 * r, sw2 = e2 * r, sw3 = e3 * r;
        // e-accumulate with the SAME eq (no second emb read)
        a0.x += sw0 * eq.x; a0.y += sw0 * eq.y; a0.z += sw0 * eq.z; a0.w += sw0 * eq.w;
        a1.x += sw1 * eq.x; a1.y += sw1 * eq.y; a1.z += sw1 * eq.z; a1.w += sw1 * eq.w;
        a2.x += sw2 * eq.x; a2.y += sw2 * eq.y; a2.z += sw2 * eq.z; a2.w += sw2 * eq.w;
        a3.x += sw3 * eq.x; a3.y += sw3 * eq.y; a3.z += sw3 * eq.z; a3.w += sw3 * eq.w;
        t0 += sw0; t1 += sw1; t2 += sw2; t3 += sw3;
      }
      RED_GRP(a0.x) RED_GRP(a0.y) RED_GRP(a0.z) RED_GRP(a0.w)
      RED_GRP(a1.x) RED_GRP(a1.y) RED_GRP(a1.z) RED_GRP(a1.w)
      RED_GRP(a2.x) RED_GRP(a2.y) RED_GRP(a2.z) RED_GRP(a2.w)
      RED_GRP(a3.x) RED_GRP(a3.y) RED_GRP(a3.z) RED_GRP(a3.w)
      RED_GRP(t0) RED_GRP(t1) RED_GRP(t2) RED_GRP(t3)
    }
    if (l < 16) {
      *(float4*)&pe[w][0][4 * l] = a0;
      *(float4*)&pe[w][1][4 * l] = a1;
      *(float4*)&pe[w][2][4 * l] = a2;
      *(float4*)&pe[w][3][4 * l] = a3;
    }
    if (l == 0) { pts[w][0] = t0; pts[w][1] = t1; pts[w][2] = t2; pts[w][3] = t3; }
    __syncthreads();

    // ---- E1 (8 waves): wave (ke,h) reduces its 32-col half, dots wreg ----
    {
      int cl = 32 * h_ + (l & 31);
      float sse = 0.f;
#pragma unroll
      for (int w2 = 0; w2 < 8; ++w2) sse += pe[w2][ke][cl];
      su[ke][cl] = sse;  // same-wave write -> broadcast read (own half only)
      float vp = 0.f;
#pragma unroll
      for (int q2 = 0; q2 < 8; ++q2) {
        float4 e4 = *(const float4*)&su[ke][32 * h_ + 4 * q2];  // broadcast
        vp += e4.x * wreg[4 * q2 + 0] + e4.y * wreg[4 * q2 + 1] +
              e4.z * wreg[4 * q2 + 2] + e4.w * wreg[4 * q2 + 3];
      }
      if (h_) spv[ke][l] = vp;
      __syncthreads();

      // ---- E2 (waves 0-3): combine, squash, update G, fold A + soff ----
      if (h_ == 0) {
        float ts_ = 0.f;
#pragma unroll
        for (int w2 = 0; w2 < 8; ++w2) ts_ += pts[w2][ke];
        float accv = vp + spv[ke][l] + ts_ * breg;
        float n2 = wred64(accv * accv);
        float scale = n2 / (1.f + n2) / sqrtf(n2 + 1e-9f);
        float inter = scale * accv;
        if (it < 2) {
          float gnew = (it == 0) ? inter : (sG[ke][l] + inter);
          sG[ke][l] = gnew;
          float ob = wred64(breg * gnew);
          if (l == 0) soff[ke] = ob;
          // A-fold: su[k][l] = W-row-l (cols 64k..) . G[k]
          const float4* Wr =
              (const float4*)(W + (size_t)l * (NK * ND) + ke * ND);
          const float4* Gk = (const float4*)&sG[ke][0];  // same-wave broadcast
          float a = 0.f;
#pragma unroll
          for (int d4 = 0; d4 < 16; ++d4) {
            float4 wv = Wr[d4], gv = Gk[d4];
            a += wv.x * gv.x + wv.y * gv.y + wv.z * gv.z + wv.w * gv.w;
          }
          su[ke][l] = a;
        } else {
          out[((size_t)b * NK + ke) * ND + l] = inter;
          float dot_ = wred64(inter * iq);
          spv[ke][l] = inter;  // stash for argmax gather (read then overwritten
                               // by same wave; h1's vp values already consumed)
          if (l == 0) satt[ke] = dot_;
        }
      }
      __syncthreads();
    }
  }

  // ---- readout: first-max argmax (== np.argmax) + gather ----
  if (t == 0) {
    int bi = 0;
    float bv = satt[0];
#pragma unroll
    for (int kk = 1; kk < NK; ++kk)
      if (satt[kk] > bv) { bv = satt[kk]; bi = kk; }
    sidx = bi;
  }
  __syncthreads();
  if (t < ND) out[(size_t)NB * NK * ND + (size_t)b * ND + t] = spv[sidx][t];
}

extern "C" void kernel_launch(void* const* d_in, const int* in_sizes, int n_in,
                              void* d_out, int out_size, void* d_ws, size_t ws_size,
                              hipStream_t stream) {
  (void)in_sizes; (void)n_in; (void)out_size; (void)d_ws; (void)ws_size;
  const float* his = (const float*)d_in[0];
  const float* itemeb = (const float*)d_in[1];
  const int* mask = (const int*)d_in[2];
  const float* W = (const float*)d_in[3];
  const float* bias = (const float*)d_in[4];
  float* out = (float*)d_out;
  caps_kernel<<<NB, NT, 0, stream>>>(his, itemeb, mask, W, bias, out);
}

// Round 11
// 88.929 us; speedup vs baseline: 1.6383x; 1.6383x over previous
//
#include <hip/hip_runtime.h>

// CapsuleNetwork routing, fused, one block per batch. B=2048, S=200, D=64, K=4.
//
// hat[b,k,s,:] = emb[b,s,:] @ W_k + b_k is never materialized:
//   logits[k,s] = emb[s]·u[k] + off[k],  u[k] = W_k @ G[k], off[k] = b_k·G[k]
//   v[k]        = e[k] @ W_k + ts[k]·b_k, e[k] = sum_s sw[k,s] emb[s]
// G = running sum of interests (cw telescopes).
//
// Round-11 = round-10's fused-BD dataflow (emb read ONCE per row per iter,
// u[k] in 16 VGPRs -> su reads 256->4 per wave-iter) with the round-10 bug
// fixed: __shfl_xor is a DS-pipe op (ds_swizzle) — its butterfly ADDED LDS
// work. All cross-lane reductions now run on the VALU:
//   lane map g=l&3 (row-quad), j=l>>2 (chunk):
//   - chunk reduce (bits 2-5): row_ror:4/8 DPP + permlane16/32_swap
//   - quad e-reduce (bits 0,1): quad_perm xor1/xor2 DPP
//   - wred64: all six steps DPP/permlane.
// DS pipe keeps only: staging DMA, 1 emb b128/row, 4 su b128/iter, pe/pts/E.

#define NB 2048
#define NS 200
#define ND 64
#define NK 4
#define NT 512

__device__ __forceinline__ int rot(int s) { return (s + (s >> 3)) & 15; }

__device__ __forceinline__ void gload16(const float* g_, float* l_) {
  __builtin_amdgcn_global_load_lds(
      (const __attribute__((address_space(1))) unsigned int*)g_,
      (__attribute__((address_space(3))) unsigned int*)l_, 16, 0, 0);
}

template <int CTRL>
__device__ __forceinline__ float dppadd(float v) {
  int p = __builtin_amdgcn_update_dpp(0, __float_as_int(v), CTRL, 0xF, 0xF, true);
  return v + __int_as_float(p);
}

#if __has_builtin(__builtin_amdgcn_permlane16_swap)
__device__ __forceinline__ float pl16add(float v) {
  auto r = __builtin_amdgcn_permlane16_swap(__float_as_int(v), __float_as_int(v),
                                            false, false);
  return __int_as_float(r[0]) + __int_as_float(r[1]);
}
#else
__device__ __forceinline__ float pl16add(float v) { return v + __shfl_xor(v, 16, 64); }
#endif

#if __has_builtin(__builtin_amdgcn_permlane32_swap)
__device__ __forceinline__ float pl32add(float v) {
  auto r = __builtin_amdgcn_permlane32_swap(__float_as_int(v), __float_as_int(v),
                                            false, false);
  return __int_as_float(r[0]) + __int_as_float(r[1]);
}
#else
__device__ __forceinline__ float pl32add(float v) { return v + __shfl_xor(v, 32, 64); }
#endif

// sum over lane bits 2..5 (the 16 chunk positions); every lane gets the total
__device__ __forceinline__ float red_j(float v) {
  v = dppadd<0x124>(v);  // row_ror:4  (bit 2)
  v = dppadd<0x128>(v);  // row_ror:8  (bit 3)
  v = pl16add(v);        // bit 4
  v = pl32add(v);        // bit 5
  return v;
}
// sum over lane bits 0,1 (row-quad)
__device__ __forceinline__ float red_q(float v) {
  v = dppadd<0xB1>(v);  // quad_perm [1,0,3,2] = xor1
  v = dppadd<0x4E>(v);  // quad_perm [2,3,0,1] = xor2
  return v;
}
// full 64-lane sum, all lanes get the result
__device__ __forceinline__ float red64(float v) { return red_j(red_q(v)); }

__global__ __launch_bounds__(NT, 2) void caps_kernel(
    const float* __restrict__ his, const float* __restrict__ itemeb,
    const int* __restrict__ mask, const float* __restrict__ W,
    const float* __restrict__ bias, float* __restrict__ out) {
  __shared__ float semb[NS * ND];  // 51200B: row s, chunk c at slot (c+rot(s))&15
  __shared__ float pe[8][NK][ND];  // 8192B: per-wave fused-BD partials
  __shared__ float sG[NK][ND];     // 1024B: running interest sum
  __shared__ float su[NK][ND];     // 1024B: u[k]; E1 se-bounce
  __shared__ float spv[NK][ND];    // 1024B: E h1 partials; interest stash
  __shared__ float smsk[NS];       // 800B
  __shared__ float4 pts4[8];       // 128B
  __shared__ __align__(16) float soff[NK];
  __shared__ float satt[NK];
  __shared__ int sidx;
  // total ~63.4 KB -> 2 blocks/CU

  const int t = threadIdx.x;
  const int w = t >> 6, l = t & 63;
  const int g = l & 3, j = l >> 2;   // row-quad / chunk (DPP-aligned mapping)
  const int gid = (w << 2) | g;      // 0..31
  const int ke = w & 3, h_ = w >> 2; // E roles
  const int b = blockIdx.x;
  const float* eb = his + (size_t)b * NS * ND;

  // ---- W slice in regs: wave (ke,h) owns W[32h..32h+32)[64ke+l] ----
  float wreg[32];
#pragma unroll
  for (int c = 0; c < 32; ++c)
    wreg[c] = W[(size_t)(32 * h_ + c) * (NK * ND) + ke * ND + l];
  float breg = bias[ke * ND + l];
  float iq = itemeb[(size_t)b * ND + l];

  // ---- stage all 200 rows (linear LDS dest, rotated global source) ----
  {
    const int sg = l >> 4, sj = l & 15;  // staging-local lane roles
    for (int i = w; i < 50; i += 8) {
      int s = 4 * i + sg;
      int q = (sj - rot(s)) & 15;  // global chunk that lands at slot sj
      gload16(eb + (s << 6) + (q << 2), &semb[i * 256]);
    }
  }
  if (t < NS) smsk[t] = (mask[(size_t)b * NS + t] != 0) ? 1.0f : 0.0f;
  __syncthreads();

  const int ntr = (w < 2) ? 7 : 6;  // wave-uniform trips (gid<8 covers s=199)

  for (int it = 0; it < 3; ++it) {
    // ---- fused BD sweep: logits + softmax + e-accumulate, one emb read ----
    float4 a0 = {0, 0, 0, 0}, a1 = {0, 0, 0, 0}, a2 = {0, 0, 0, 0},
           a3 = {0, 0, 0, 0};
    float t0 = 0, t1 = 0, t2 = 0, t3 = 0;

    if (it == 0) {
      for (int tt = 0; tt < ntr; ++tt) {
        int s = gid + 32 * tt;
        float4 eq = *(const float4*)&semb[(s << 6) + 4 * ((j + rot(s)) & 15)];
        float sw = 0.25f * smsk[s];
        a0.x += sw * eq.x; a0.y += sw * eq.y;
        a0.z += sw * eq.z; a0.w += sw * eq.w;
        t0 += sw;
      }
      a0.x = red_q(a0.x); a0.y = red_q(a0.y);
      a0.z = red_q(a0.z); a0.w = red_q(a0.w);
      t0 = red_q(t0);
      a1 = a0; a2 = a0; a3 = a0; t1 = t0; t2 = t0; t3 = t0;
    } else {
      float4 u0 = *(const float4*)&su[0][4 * j];  // u chunks -> 16 VGPR
      float4 u1 = *(const float4*)&su[1][4 * j];
      float4 u2 = *(const float4*)&su[2][4 * j];
      float4 u3 = *(const float4*)&su[3][4 * j];
      float4 sof = *(const float4*)&soff[0];      // wave-broadcast
      for (int tt = 0; tt < ntr; ++tt) {
        int s = gid + 32 * tt;
        float4 eq = *(const float4*)&semb[(s << 6) + 4 * ((j + rot(s)) & 15)];
        float mk = smsk[s];
        // per-chunk logit partials; reduce over chunks on the VALU
        float lg0 = eq.x * u0.x + eq.y * u0.y + eq.z * u0.z + eq.w * u0.w;
        float lg1 = eq.x * u1.x + eq.y * u1.y + eq.z * u1.z + eq.w * u1.w;
        float lg2 = eq.x * u2.x + eq.y * u2.y + eq.z * u2.z + eq.w * u2.w;
        float lg3 = eq.x * u3.x + eq.y * u3.y + eq.z * u3.z + eq.w * u3.w;
        lg0 = red_j(lg0) + sof.x;
        lg1 = red_j(lg1) + sof.y;
        lg2 = red_j(lg2) + sof.z;
        lg3 = red_j(lg3) + sof.w;
        // in-lane softmax over k (redundant across the 16 chunk-lanes)
        float mx = fmaxf(fmaxf(lg0, lg1), fmaxf(lg2, lg3));
        float e0 = __expf(lg0 - mx), e1 = __expf(lg1 - mx);
        float e2 = __expf(lg2 - mx), e3 = __expf(lg3 - mx);
        float r = mk / (e0 + e1 + e2 + e3);
        float sw0 = e0 * r, sw1 = e1 * r, sw2 = e2 * r, sw3 = e3 * r;
        a0.x += sw0 * eq.x; a0.y += sw0 * eq.y; a0.z += sw0 * eq.z; a0.w += sw0 * eq.w;
        a1.x += sw1 * eq.x; a1.y += sw1 * eq.y; a1.z += sw1 * eq.z; a1.w += sw1 * eq.w;
        a2.x += sw2 * eq.x; a2.y += sw2 * eq.y; a2.z += sw2 * eq.z; a2.w += sw2 * eq.w;
        a3.x += sw3 * eq.x; a3.y += sw3 * eq.y; a3.z += sw3 * eq.z; a3.w += sw3 * eq.w;
        t0 += sw0; t1 += sw1; t2 += sw2; t3 += sw3;
      }
      // quad (cross-row-group) reduce on the VALU
      a0.x = red_q(a0.x); a0.y = red_q(a0.y); a0.z = red_q(a0.z); a0.w = red_q(a0.w);
      a1.x = red_q(a1.x); a1.y = red_q(a1.y); a1.z = red_q(a1.z); a1.w = red_q(a1.w);
      a2.x = red_q(a2.x); a2.y = red_q(a2.y); a2.z = red_q(a2.z); a2.w = red_q(a2.w);
      a3.x = red_q(a3.x); a3.y = red_q(a3.y); a3.z = red_q(a3.z); a3.w = red_q(a3.w);
      t0 = red_q(t0); t1 = red_q(t1); t2 = red_q(t2); t3 = red_q(t3);
    }
    if (g == 0) {  // 16 lanes, one float4 per chunk j
      *(float4*)&pe[w][0][4 * j] = a0;
      *(float4*)&pe[w][1][4 * j] = a1;
      *(float4*)&pe[w][2][4 * j] = a2;
      *(float4*)&pe[w][3][4 * j] = a3;
    }
    if (l == 0) pts4[w] = make_float4(t0, t1, t2, t3);
    __syncthreads();

    // ---- E1 (8 waves): wave (ke,h) reduces its 32-col half, dots wreg ----
    {
      int cl = 32 * h_ + (l & 31);
      float sse = 0.f;
#pragma unroll
      for (int w2 = 0; w2 < 8; ++w2) sse += pe[w2][ke][cl];
      su[ke][cl] = sse;  // same-wave write -> broadcast read (own half only)
      float vp = 0.f;
#pragma unroll
      for (int q2 = 0; q2 < 8; ++q2) {
        float4 e4 = *(const float4*)&su[ke][32 * h_ + 4 * q2];  // broadcast
        vp += e4.x * wreg[4 * q2 + 0] + e4.y * wreg[4 * q2 + 1] +
              e4.z * wreg[4 * q2 + 2] + e4.w * wreg[4 * q2 + 3];
      }
      if (h_) spv[ke][l] = vp;
      __syncthreads();

      // ---- E2 (waves 0-3): combine, squash, update G, fold A + soff ----
      if (h_ == 0) {
        float ts_ = 0.f;
#pragma unroll
        for (int w2 = 0; w2 < 8; ++w2) ts_ += ((const float*)&pts4[w2])[ke];
        float accv = vp + spv[ke][l] + ts_ * breg;
        float n2 = red64(accv * accv);
        float scale = n2 / (1.f + n2) / sqrtf(n2 + 1e-9f);
        float inter = scale * accv;
        if (it < 2) {
          float gnew = (it == 0) ? inter : (sG[ke][l] + inter);
          sG[ke][l] = gnew;
          float ob = red64(breg * gnew);
          if (l == 0) soff[ke] = ob;
          // A-fold: su[k][l] = W-row-l (cols 64k..) . G[k]
          const float4* Wr =
              (const float4*)(W + (size_t)l * (NK * ND) + ke * ND);
          const float4* Gk = (const float4*)&sG[ke][0];  // same-wave broadcast
          float a = 0.f;
#pragma unroll
          for (int d4 = 0; d4 < 16; ++d4) {
            float4 wv = Wr[d4], gv = Gk[d4];
            a += wv.x * gv.x + wv.y * gv.y + wv.z * gv.z + wv.w * gv.w;
          }
          su[ke][l] = a;
        } else {
          out[((size_t)b * NK + ke) * ND + l] = inter;
          float dot_ = red64(inter * iq);
          spv[ke][l] = inter;  // stash for argmax gather
          if (l == 0) satt[ke] = dot_;
        }
      }
      __syncthreads();
    }
  }

  // ---- readout: first-max argmax (== np.argmax) + gather ----
  if (t == 0) {
    int bi = 0;
    float bv = satt[0];
#pragma unroll
    for (int kk = 1; kk < NK; ++kk)
      if (satt[kk] > bv) { bv = satt[kk]; bi = kk; }
    sidx = bi;
  }
  __syncthreads();
  if (t < ND) out[(size_t)NB * NK * ND + (size_t)b * ND + t] = spv[sidx][t];
}

extern "C" void kernel_launch(void* const* d_in, const int* in_sizes, int n_in,
                              void* d_out, int out_size, void* d_ws, size_t ws_size,
                              hipStream_t stream) {
  (void)in_sizes; (void)n_in; (void)out_size; (void)d_ws; (void)ws_size;
  const float* his = (const float*)d_in[0];
  const float* itemeb = (const float*)d_in[1];
  const int* mask = (const int*)d_in[2];
  const float* W = (const float*)d_in[3];
  const float* bias = (const float*)d_in[4];
  float* out = (float*)d_out;
  caps_kernel<<<NB, NT, 0, stream>>>(his, itemeb, mask, W, bias, out);
}